// Round 1
// baseline (343.997 us; speedup 1.0000x reference)
//
#include <hip/hip_runtime.h>

// EdgeAttrPredictor: per-edge MLP.
// out[e] = relu2 @ W3 + b3 + x_cat @ Wd + bd
//   x_cat = [min(x[s],x[t]), max(x[s],x[t])]  (128)
//   h1 = relu(x_cat @ W1 + b1)                 (32)
//   h2 = relu(h1 @ W2 + b2 + h1)               (32)
constexpr int HID = 32;

__global__ __launch_bounds__(256) void edge_pred_kernel(
    const float* __restrict__ x,
    const int* __restrict__ ei,
    const float* __restrict__ Wd, const float* __restrict__ bd,
    const float* __restrict__ W1, const float* __restrict__ b1,
    const float* __restrict__ W2, const float* __restrict__ b2,
    const float* __restrict__ W3, const float* __restrict__ b3,
    float* __restrict__ out, int E)
{
    int e = blockIdx.x * blockDim.x + threadIdx.x;
    if (e >= E) return;

    int s = ei[e];
    int t = ei[E + e];
    const float4* __restrict__ xs4 = (const float4*)(x + (long)s * 64);
    const float4* __restrict__ xt4 = (const float4*)(x + (long)t * 64);

    float h[HID];
    #pragma unroll
    for (int j = 0; j < HID; ++j) h[j] = b1[j];
    float d0 = bd[0], d1 = bd[1], d2 = bd[2], d3 = bd[3];

    // x_cat @ W1 (rows 0..63 multiply min, 64..127 multiply max)
    // and x_cat @ Wd, streamed over 16 float4 chunks of the latent dim.
    #pragma unroll 2
    for (int c = 0; c < 16; ++c) {
        float4 a = xs4[c];
        float4 b = xt4[c];
        float mn[4] = {fminf(a.x, b.x), fminf(a.y, b.y), fminf(a.z, b.z), fminf(a.w, b.w)};
        float mx[4] = {fmaxf(a.x, b.x), fmaxf(a.y, b.y), fmaxf(a.z, b.z), fmaxf(a.w, b.w)};
        #pragma unroll
        for (int q = 0; q < 4; ++q) {
            int l = c * 4 + q;
            const float* __restrict__ wlo = W1 + l * HID;        // min row
            const float* __restrict__ whi = W1 + (64 + l) * HID; // max row
            #pragma unroll
            for (int j = 0; j < HID; ++j) {
                h[j] += mn[q] * wlo[j];
                h[j] += mx[q] * whi[j];
            }
            const float* __restrict__ dlo = Wd + l * 4;
            const float* __restrict__ dhi = Wd + (64 + l) * 4;
            d0 += mn[q] * dlo[0] + mx[q] * dhi[0];
            d1 += mn[q] * dlo[1] + mx[q] * dhi[1];
            d2 += mn[q] * dlo[2] + mx[q] * dhi[2];
            d3 += mn[q] * dlo[3] + mx[q] * dhi[3];
        }
    }

    float h1[HID];
    #pragma unroll
    for (int j = 0; j < HID; ++j) h1[j] = fmaxf(h[j], 0.0f);

    // residual block: h2 = relu(h1 @ W2 + b2 + h1)
    float s2[HID];
    #pragma unroll
    for (int j = 0; j < HID; ++j) s2[j] = b2[j] + h1[j];
    #pragma unroll 4
    for (int k = 0; k < HID; ++k) {
        const float* __restrict__ w2r = W2 + k * HID;
        #pragma unroll
        for (int j = 0; j < HID; ++j) s2[j] += h1[k] * w2r[j];
    }

    float o0 = b3[0] + d0, o1 = b3[1] + d1, o2 = b3[2] + d2, o3 = b3[3] + d3;
    #pragma unroll
    for (int k = 0; k < HID; ++k) {
        float hk = fmaxf(s2[k], 0.0f);
        const float* __restrict__ w3r = W3 + k * 4;
        o0 += hk * w3r[0];
        o1 += hk * w3r[1];
        o2 += hk * w3r[2];
        o3 += hk * w3r[3];
    }

    *(float4*)(out + (long)e * 4) = make_float4(o0, o1, o2, o3);
}

extern "C" void kernel_launch(void* const* d_in, const int* in_sizes, int n_in,
                              void* d_out, int out_size, void* d_ws, size_t ws_size,
                              hipStream_t stream) {
    const float* x  = (const float*)d_in[0];
    const int*   ei = (const int*)d_in[1];
    const float* Wd = (const float*)d_in[2];
    const float* bd = (const float*)d_in[3];
    const float* W1 = (const float*)d_in[4];
    const float* b1 = (const float*)d_in[5];
    const float* W2 = (const float*)d_in[6];
    const float* b2 = (const float*)d_in[7];
    const float* W3 = (const float*)d_in[8];
    const float* b3 = (const float*)d_in[9];
    float* out = (float*)d_out;

    int E = in_sizes[1] / 2;
    const int block = 256;
    const int grid = (E + block - 1) / block;
    hipLaunchKernelGGL(edge_pred_kernel, dim3(grid), dim3(block), 0, stream,
                       x, ei, Wd, bd, W1, b1, W2, b2, W3, b3, out, E);
}

// Round 3
// 101.302 us; speedup vs baseline: 3.3957x; 3.3957x over previous
//
#include <hip/hip_runtime.h>

typedef __attribute__((ext_vector_type(8))) short short8;       // 8 x bf16 (4 VGPR)
typedef __attribute__((ext_vector_type(4))) float f32x4;         // MFMA acc
typedef __attribute__((ext_vector_type(4))) unsigned int u32x4;

constexpr int HID = 32;
constexpr int LAT = 64;    // latent dim
constexpr int EPB = 256;   // edges per block (4 waves x 4 tiles x 16 edges)
constexpr int NFRAG = 12;  // 4 k-steps x 3 N-tiles of W1aug [128 x 48]
constexpr int HLS_STRIDE = 37; // 32 h cols + 4 direct cols + 1 pad

// ---------- helpers ----------
__device__ __forceinline__ unsigned bf16rne(float f) {
    unsigned u = __float_as_uint(f);
    return (u + 0x7FFFu + ((u >> 16) & 1u)) >> 16;
}
__device__ __forceinline__ unsigned pk2(float lo, float hi) {   // pack 2 f32 -> 2 bf16 (RNE)
    return bf16rne(lo) | (bf16rne(hi) << 16);
}
// packed-bf16-pair min/max (inputs are exact bf16 values; results exact)
__device__ __forceinline__ void mnmx_word(unsigned a, unsigned b, unsigned& mn, unsigned& mx) {
    float al = __uint_as_float(a << 16), ah = __uint_as_float(a & 0xFFFF0000u);
    float bl = __uint_as_float(b << 16), bh = __uint_as_float(b & 0xFFFF0000u);
    mn = (__float_as_uint(fminf(al, bl)) >> 16) | (__float_as_uint(fminf(ah, bh)) & 0xFFFF0000u);
    mx = (__float_as_uint(fmaxf(al, bl)) >> 16) | (__float_as_uint(fmaxf(ah, bh)) & 0xFFFF0000u);
}
struct MnMx4 { unsigned w0, w1, x0, x1; };
__device__ __forceinline__ MnMx4 mnmx4(float4 a, float4 b) {
    MnMx4 r;
    r.w0 = pk2(fminf(a.x, b.x), fminf(a.y, b.y));
    r.w1 = pk2(fminf(a.z, b.z), fminf(a.w, b.w));
    r.x0 = pk2(fmaxf(a.x, b.x), fmaxf(a.y, b.y));
    r.x1 = pk2(fmaxf(a.z, b.z), fmaxf(a.w, b.w));
    return r;
}

// ---------- pre-pass: x fp32 -> bf16 ----------
__global__ __launch_bounds__(256) void cvt_x_kernel(const float* __restrict__ x,
                                                    unsigned short* __restrict__ xb, int n8) {
    int i = blockIdx.x * blockDim.x + threadIdx.x;
    if (i >= n8) return;
    const float4* p = (const float4*)x + (long)i * 2;
    float4 a = p[0], b = p[1];
    u32x4 v = { pk2(a.x, a.y), pk2(a.z, a.w), pk2(b.x, b.y), pk2(b.z, b.w) };
    ((u32x4*)xb)[i] = v;
}

// ---------- pre-pass: build W1aug B-fragments ----------
// frag ft = s*3+t (k-step s, N-tile t). Lane l holds B[k = s*32 + (l>>4)*8 + i][col 16t + (l&15)],
// i = 0..7 packed as bf16x8. Tile 2 cols: 0-3 = Wd, 4-15 = zero.
__global__ __launch_bounds__(256) void build_frags_kernel(const float* __restrict__ W1,
                                                          const float* __restrict__ Wd,
                                                          unsigned short* __restrict__ fr) {
    int id = blockIdx.x * blockDim.x + threadIdx.x;
    if (id >= NFRAG * 64) return;
    int l = id & 63;
    int ft = id >> 6;
    int s = ft / 3, t = ft - s * 3;
    int g = l >> 4, c = l & 15;
    unsigned w[4];
    #pragma unroll
    for (int q = 0; q < 4; ++q) {
        int k = s * 32 + g * 8 + q * 2;
        float lo, hi;
        if (t < 2) { lo = W1[k * HID + t * 16 + c]; hi = W1[(k + 1) * HID + t * 16 + c]; }
        else { lo = (c < 4) ? Wd[k * 4 + c] : 0.0f; hi = (c < 4) ? Wd[(k + 1) * 4 + c] : 0.0f; }
        w[q] = pk2(lo, hi);
    }
    u32x4 v = { w[0], w[1], w[2], w[3] };
    ((u32x4*)fr)[ft * 64 + l] = v;
}

// ---------- main kernel ----------
// XMODE 1: gather bf16 x from ws; XMODE 0: gather fp32 x directly.
template<int XMODE>
__global__ __launch_bounds__(256) void edge_mfma_kernel(
    const float* __restrict__ xf,
    const unsigned short* __restrict__ xb,
    const unsigned short* __restrict__ fr,
    const int* __restrict__ ei,
    const float* __restrict__ b1, const float* __restrict__ bd,
    const float* __restrict__ W2, const float* __restrict__ b2,
    const float* __restrict__ W3, const float* __restrict__ b3,
    float* __restrict__ out, int E)
{
    __shared__ float hls[EPB][HLS_STRIDE];
    const int tid = threadIdx.x;
    const int l = tid & 63;
    const int wv = tid >> 6;
    const int g = l >> 4, r = l & 15;
    const long blockBase = (long)blockIdx.x * EPB;

    // W1aug B-fragments, resident for the whole kernel (48 VGPR)
    short8 bfr[NFRAG];
    #pragma unroll
    for (int f = 0; f < NFRAG; ++f) bfr[f] = ((const short8*)fr)[f * 64 + l];

    #pragma unroll
    for (int tile = 0; tile < 4; ++tile) {
        long e = blockBase + wv * 64 + tile * 16 + r;
        long ecl = (e < E) ? e : (long)(E - 1);
        int si = ei[ecl];
        int ti = ei[(long)E + ecl];

        // A fragments: af0/af1 = min(lo/hi elems), af2/af3 = max(lo/hi elems)
        // slot i of step s <-> k = s*32 + g*8 + i  (same convention as B frags)
        union { short8 s; u32x4 u; } af0, af1, af2, af3;
        if (XMODE == 1) {
            const u32x4* ps = (const u32x4*)(xb + (long)si * LAT);
            const u32x4* pt = (const u32x4*)(xb + (long)ti * LAT);
            u32x4 sl = ps[g], sh = ps[4 + g];
            u32x4 tl = pt[g], th = pt[4 + g];
            #pragma unroll
            for (int q = 0; q < 4; ++q) {
                unsigned mn, mx;
                mnmx_word(sl[q], tl[q], mn, mx);
                af0.u[q] = mn; af2.u[q] = mx;
                mnmx_word(sh[q], th[q], mn, mx);
                af1.u[q] = mn; af3.u[q] = mx;
            }
        } else {
            const float4* ps = (const float4*)(xf + (long)si * LAT);
            const float4* pt = (const float4*)(xf + (long)ti * LAT);
            float4 sa = ps[2 * g], sb = ps[2 * g + 1], sc = ps[8 + 2 * g], sd = ps[9 + 2 * g];
            float4 ta = pt[2 * g], tb = pt[2 * g + 1], tc = pt[8 + 2 * g], td = pt[9 + 2 * g];
            MnMx4 m0 = mnmx4(sa, ta);
            MnMx4 m1 = mnmx4(sb, tb);
            MnMx4 m2 = mnmx4(sc, tc);
            MnMx4 m3 = mnmx4(sd, td);
            af0.u[0] = m0.w0; af0.u[1] = m0.w1; af2.u[0] = m0.x0; af2.u[1] = m0.x1;
            af0.u[2] = m1.w0; af0.u[3] = m1.w1; af2.u[2] = m1.x0; af2.u[3] = m1.x1;
            af1.u[0] = m2.w0; af1.u[1] = m2.w1; af3.u[0] = m2.x0; af3.u[1] = m2.x1;
            af1.u[2] = m3.w0; af1.u[3] = m3.w1; af3.u[2] = m3.x0; af3.u[3] = m3.x1;
        }

        f32x4 a0 = {0.f, 0.f, 0.f, 0.f}, a1 = a0, a2 = a0;
        a0 = __builtin_amdgcn_mfma_f32_16x16x32_bf16(af0.s, bfr[0],  a0, 0, 0, 0);
        a1 = __builtin_amdgcn_mfma_f32_16x16x32_bf16(af0.s, bfr[1],  a1, 0, 0, 0);
        a2 = __builtin_amdgcn_mfma_f32_16x16x32_bf16(af0.s, bfr[2],  a2, 0, 0, 0);
        a0 = __builtin_amdgcn_mfma_f32_16x16x32_bf16(af1.s, bfr[3],  a0, 0, 0, 0);
        a1 = __builtin_amdgcn_mfma_f32_16x16x32_bf16(af1.s, bfr[4],  a1, 0, 0, 0);
        a2 = __builtin_amdgcn_mfma_f32_16x16x32_bf16(af1.s, bfr[5],  a2, 0, 0, 0);
        a0 = __builtin_amdgcn_mfma_f32_16x16x32_bf16(af2.s, bfr[6],  a0, 0, 0, 0);
        a1 = __builtin_amdgcn_mfma_f32_16x16x32_bf16(af2.s, bfr[7],  a1, 0, 0, 0);
        a2 = __builtin_amdgcn_mfma_f32_16x16x32_bf16(af2.s, bfr[8],  a2, 0, 0, 0);
        a0 = __builtin_amdgcn_mfma_f32_16x16x32_bf16(af3.s, bfr[9],  a0, 0, 0, 0);
        a1 = __builtin_amdgcn_mfma_f32_16x16x32_bf16(af3.s, bfr[10], a1, 0, 0, 0);
        a2 = __builtin_amdgcn_mfma_f32_16x16x32_bf16(af3.s, bfr[11], a2, 0, 0, 0);

        // C/D layout (verified m89): col = lane&15, row = (lane>>4)*4 + reg
        int rowbase = wv * 64 + tile * 16 + g * 4;
        #pragma unroll
        for (int p = 0; p < 4; ++p) {
            hls[rowbase + p][r]      = a0[p];
            hls[rowbase + p][16 + r] = a1[p];
        }
        if (r < 4) {
            #pragma unroll
            for (int p = 0; p < 4; ++p) hls[rowbase + p][32 + r] = a2[p];
        }
    }

    // No __syncthreads needed: each wave reads back exactly the rows it wrote
    // (thread t reads row t; rows [wv*64, wv*64+64) were written by wave wv = t>>6).

    float h1[HID];
    #pragma unroll
    for (int j = 0; j < HID; ++j) h1[j] = fmaxf(hls[tid][j] + b1[j], 0.0f);
    float dp0 = hls[tid][32] + bd[0], dp1 = hls[tid][33] + bd[1];
    float dp2 = hls[tid][34] + bd[2], dp3 = hls[tid][35] + bd[3];

    float s2[HID];
    #pragma unroll
    for (int j = 0; j < HID; ++j) s2[j] = b2[j] + h1[j];
    #pragma unroll 8
    for (int k = 0; k < HID; ++k) {
        const float* __restrict__ w2r = W2 + k * HID;
        float hk = h1[k];
        #pragma unroll
        for (int j = 0; j < HID; ++j) s2[j] = fmaf(hk, w2r[j], s2[j]);
    }
    float o0 = b3[0] + dp0, o1 = b3[1] + dp1, o2 = b3[2] + dp2, o3 = b3[3] + dp3;
    #pragma unroll
    for (int k = 0; k < HID; ++k) {
        float hk = fmaxf(s2[k], 0.0f);
        const float* __restrict__ w3r = W3 + k * 4;
        o0 = fmaf(hk, w3r[0], o0);
        o1 = fmaf(hk, w3r[1], o1);
        o2 = fmaf(hk, w3r[2], o2);
        o3 = fmaf(hk, w3r[3], o3);
    }
    long e = blockBase + tid;
    if (e < E) *(float4*)(out + e * 4) = make_float4(o0, o1, o2, o3);
}

// ---------- fallback (tiny ws): round-1 fp32 per-thread kernel ----------
__global__ __launch_bounds__(256) void edge_pred_fp32_kernel(
    const float* __restrict__ x, const int* __restrict__ ei,
    const float* __restrict__ Wd, const float* __restrict__ bd,
    const float* __restrict__ W1, const float* __restrict__ b1,
    const float* __restrict__ W2, const float* __restrict__ b2,
    const float* __restrict__ W3, const float* __restrict__ b3,
    float* __restrict__ out, int E)
{
    int e = blockIdx.x * blockDim.x + threadIdx.x;
    if (e >= E) return;
    int s = ei[e];
    int t = ei[E + e];
    const float4* xs4 = (const float4*)(x + (long)s * 64);
    const float4* xt4 = (const float4*)(x + (long)t * 64);
    float h[HID];
    #pragma unroll
    for (int j = 0; j < HID; ++j) h[j] = b1[j];
    float d0 = bd[0], d1 = bd[1], d2 = bd[2], d3 = bd[3];
    #pragma unroll 2
    for (int c = 0; c < 16; ++c) {
        float4 a = xs4[c];
        float4 b = xt4[c];
        float mn[4] = {fminf(a.x,b.x), fminf(a.y,b.y), fminf(a.z,b.z), fminf(a.w,b.w)};
        float mx[4] = {fmaxf(a.x,b.x), fmaxf(a.y,b.y), fmaxf(a.z,b.z), fmaxf(a.w,b.w)};
        #pragma unroll
        for (int q = 0; q < 4; ++q) {
            int lidx = c * 4 + q;
            const float* wlo = W1 + lidx * HID;
            const float* whi = W1 + (64 + lidx) * HID;
            #pragma unroll
            for (int j = 0; j < HID; ++j) { h[j] += mn[q]*wlo[j]; h[j] += mx[q]*whi[j]; }
            const float* dlo = Wd + lidx * 4;
            const float* dhi = Wd + (64 + lidx) * 4;
            d0 += mn[q]*dlo[0] + mx[q]*dhi[0];
            d1 += mn[q]*dlo[1] + mx[q]*dhi[1];
            d2 += mn[q]*dlo[2] + mx[q]*dhi[2];
            d3 += mn[q]*dlo[3] + mx[q]*dhi[3];
        }
    }
    float h1[HID];
    #pragma unroll
    for (int j = 0; j < HID; ++j) h1[j] = fmaxf(h[j], 0.0f);
    float s2[HID];
    #pragma unroll
    for (int j = 0; j < HID; ++j) s2[j] = b2[j] + h1[j];
    #pragma unroll 4
    for (int k = 0; k < HID; ++k) {
        const float* w2r = W2 + k * HID;
        #pragma unroll
        for (int j = 0; j < HID; ++j) s2[j] += h1[k] * w2r[j];
    }
    float o0 = b3[0] + d0, o1 = b3[1] + d1, o2 = b3[2] + d2, o3 = b3[3] + d3;
    #pragma unroll
    for (int k = 0; k < HID; ++k) {
        float hk = fmaxf(s2[k], 0.0f);
        const float* w3r = W3 + k * 4;
        o0 += hk*w3r[0]; o1 += hk*w3r[1]; o2 += hk*w3r[2]; o3 += hk*w3r[3];
    }
    *(float4*)(out + (long)e * 4) = make_float4(o0, o1, o2, o3);
}

extern "C" void kernel_launch(void* const* d_in, const int* in_sizes, int n_in,
                              void* d_out, int out_size, void* d_ws, size_t ws_size,
                              hipStream_t stream) {
    const float* x  = (const float*)d_in[0];
    const int*   ei = (const int*)d_in[1];
    const float* Wd = (const float*)d_in[2];
    const float* bd = (const float*)d_in[3];
    const float* W1 = (const float*)d_in[4];
    const float* b1 = (const float*)d_in[5];
    const float* W2 = (const float*)d_in[6];
    const float* b2 = (const float*)d_in[7];
    const float* W3 = (const float*)d_in[8];
    const float* b3 = (const float*)d_in[9];
    float* out = (float*)d_out;

    int E  = in_sizes[1] / 2;
    int NN = in_sizes[0] / LAT;

    size_t fbytes = (size_t)NFRAG * 64 * 16;           // 12 KB of B-fragments
    size_t fpad   = (fbytes + 255) & ~(size_t)255;
    size_t xbytes = (size_t)NN * LAT * 2;              // bf16 x

    int grid = (E + EPB - 1) / EPB;
    if (ws_size >= fpad + xbytes) {
        unsigned short* frg = (unsigned short*)d_ws;
        unsigned short* xb  = (unsigned short*)((char*)d_ws + fpad);
        hipLaunchKernelGGL(build_frags_kernel, dim3(3), dim3(256), 0, stream, W1, Wd, frg);
        int n8 = NN * LAT / 8;
        hipLaunchKernelGGL(cvt_x_kernel, dim3((n8 + 255) / 256), dim3(256), 0, stream, x, xb, n8);
        hipLaunchKernelGGL((edge_mfma_kernel<1>), dim3(grid), dim3(256), 0, stream,
                           x, xb, frg, ei, b1, bd, W2, b2, W3, b3, out, E);
    } else if (ws_size >= fbytes) {
        unsigned short* frg = (unsigned short*)d_ws;
        hipLaunchKernelGGL(build_frags_kernel, dim3(3), dim3(256), 0, stream, W1, Wd, frg);
        hipLaunchKernelGGL((edge_mfma_kernel<0>), dim3(grid), dim3(256), 0, stream,
                           x, (const unsigned short*)nullptr, frg, ei, b1, bd, W2, b2, W3, b3, out, E);
    } else {
        hipLaunchKernelGGL(edge_pred_fp32_kernel, dim3((E + 255) / 256), dim3(256), 0, stream,
                           x, ei, Wd, bd, W1, b1, W2, b2, W3, b3, out, E);
    }
}

// Round 4
// 87.368 us; speedup vs baseline: 3.9373x; 1.1595x over previous
//
#include <hip/hip_runtime.h>

typedef __attribute__((ext_vector_type(8))) short short8;       // 8 x bf16 (4 VGPR)
typedef __attribute__((ext_vector_type(4))) float f32x4;         // MFMA acc
typedef __attribute__((ext_vector_type(4))) unsigned int u32x4;

constexpr int HID = 32;
constexpr int LAT = 64;    // latent dim
constexpr int EPB = 256;   // edges per block (4 waves x 4 tiles x 16 edges)
constexpr int NFRAG = 12;  // W1aug [128 x 48]: 4 k-steps x 3 N-tiles
constexpr int NFRAG2 = 2;  // W2aug [32 x 32]: 1 k-step x 2 N-tiles
constexpr int HW_STRIDE = 17; // u32 words per edge row (16 feat-pairs + 1 pad)

// ---------- helpers ----------
__device__ __forceinline__ unsigned bf16rne(float f) {
    unsigned u = __float_as_uint(f);
    return (u + 0x7FFFu + ((u >> 16) & 1u)) >> 16;
}
__device__ __forceinline__ unsigned pk2(float lo, float hi) {   // pack 2 f32 -> 2 bf16 (RNE)
    return bf16rne(lo) | (bf16rne(hi) << 16);
}
// packed-bf16-pair min/max (inputs are exact bf16 values; results exact)
__device__ __forceinline__ void mnmx_word(unsigned a, unsigned b, unsigned& mn, unsigned& mx) {
    float al = __uint_as_float(a << 16), ah = __uint_as_float(a & 0xFFFF0000u);
    float bl = __uint_as_float(b << 16), bh = __uint_as_float(b & 0xFFFF0000u);
    mn = (__float_as_uint(fminf(al, bl)) >> 16) | (__float_as_uint(fminf(ah, bh)) & 0xFFFF0000u);
    mx = (__float_as_uint(fmaxf(al, bl)) >> 16) | (__float_as_uint(fmaxf(ah, bh)) & 0xFFFF0000u);
}
struct MnMx4 { unsigned w0, w1, x0, x1; };
__device__ __forceinline__ MnMx4 mnmx4(float4 a, float4 b) {
    MnMx4 r;
    r.w0 = pk2(fminf(a.x, b.x), fminf(a.y, b.y));
    r.w1 = pk2(fminf(a.z, b.z), fminf(a.w, b.w));
    r.x0 = pk2(fmaxf(a.x, b.x), fmaxf(a.y, b.y));
    r.x1 = pk2(fmaxf(a.z, b.z), fmaxf(a.w, b.w));
    return r;
}

// ---------- pre-pass: x fp32 -> bf16 ----------
__global__ __launch_bounds__(256) void cvt_x_kernel(const float* __restrict__ x,
                                                    unsigned short* __restrict__ xb, int n8) {
    int i = blockIdx.x * blockDim.x + threadIdx.x;
    if (i >= n8) return;
    const float4* p = (const float4*)x + (long)i * 2;
    float4 a = p[0], b = p[1];
    u32x4 v = { pk2(a.x, a.y), pk2(a.z, a.w), pk2(b.x, b.y), pk2(b.z, b.w) };
    ((u32x4*)xb)[i] = v;
}

// ---------- pre-pass: build B-fragments ----------
// W1aug frags (ids 0..767): frag ft = s*3+t. Lane l holds B[k=s*32+(l>>4)*8+i][col 16t+(l&15)],
//   i=0..7 packed bf16x8. Tile 2: cols 0-3 = Wd, 4-15 = zero.
// W2aug frags (ids 768..895): W2+I, k-slot sigma(g, 2q+h) = 4g+q+16h (matches A-pack of h-words).
__global__ __launch_bounds__(256) void build_frags_kernel(const float* __restrict__ W1,
                                                          const float* __restrict__ Wd,
                                                          const float* __restrict__ W2,
                                                          unsigned short* __restrict__ fr,
                                                          unsigned short* __restrict__ fr2) {
    int id = blockIdx.x * blockDim.x + threadIdx.x;
    if (id < NFRAG * 64) {
        int l = id & 63;
        int ft = id >> 6;
        int s = ft / 3, t = ft - s * 3;
        int g = l >> 4, c = l & 15;
        unsigned w[4];
        #pragma unroll
        for (int q = 0; q < 4; ++q) {
            int k = s * 32 + g * 8 + q * 2;
            float lo, hi;
            if (t < 2) { lo = W1[k * HID + t * 16 + c]; hi = W1[(k + 1) * HID + t * 16 + c]; }
            else { lo = (c < 4) ? Wd[k * 4 + c] : 0.0f; hi = (c < 4) ? Wd[(k + 1) * 4 + c] : 0.0f; }
            w[q] = pk2(lo, hi);
        }
        u32x4 v = { w[0], w[1], w[2], w[3] };
        ((u32x4*)fr)[ft * 64 + l] = v;
    } else if (id < NFRAG * 64 + NFRAG2 * 64) {
        int f2 = id - NFRAG * 64;
        int l = f2 & 63;
        int t = f2 >> 6;
        int g = l >> 4, c = l & 15;
        int col = t * 16 + c;
        unsigned w[4];
        #pragma unroll
        for (int q = 0; q < 4; ++q) {
            int f0 = g * 4 + q;       // k-slot 2q   -> feature f0
            int f1 = f0 + 16;         // k-slot 2q+1 -> feature f0+16
            float lo = W2[f0 * HID + col] + (f0 == col ? 1.0f : 0.0f);
            float hi = W2[f1 * HID + col] + (f1 == col ? 1.0f : 0.0f);
            w[q] = pk2(lo, hi);
        }
        u32x4 v = { w[0], w[1], w[2], w[3] };
        ((u32x4*)fr2)[t * 64 + l] = v;
    }
}

// ---------- main kernel ----------
// XMODE 1: gather bf16 x from ws; XMODE 0: gather fp32 x directly.
template<int XMODE>
__global__ __launch_bounds__(256) void edge_mfma_kernel(
    const float* __restrict__ xf,
    const unsigned short* __restrict__ xb,
    const unsigned short* __restrict__ fr,
    const unsigned short* __restrict__ fr2,
    const int* __restrict__ ei,
    const float* __restrict__ b1, const float* __restrict__ bd,
    const float* __restrict__ b2,
    const float* __restrict__ W3, const float* __restrict__ b3,
    float* __restrict__ out, int E)
{
    __shared__ unsigned hw[EPB][HW_STRIDE];  // bf16-pair words: (feat r, feat r+16)
    __shared__ float dls[EPB][5];            // direct-path f32 partials
    const int tid = threadIdx.x;
    const int l = tid & 63;
    const int wv = tid >> 6;
    const int g = l >> 4, r = l & 15;
    const long blockBase = (long)blockIdx.x * EPB;

    // B-fragments resident in VGPRs (48 + 8)
    short8 bfr[NFRAG];
    #pragma unroll
    for (int f = 0; f < NFRAG; ++f) bfr[f] = ((const short8*)fr)[f * 64 + l];
    short8 w2f[NFRAG2];
    #pragma unroll
    for (int f = 0; f < NFRAG2; ++f) w2f[f] = ((const short8*)fr2)[f * 64 + l];

    const float b1lo = b1[r], b1hi = b1[16 + r];
    const float b2lo = b2[r], b2hi = b2[16 + r];

    #pragma unroll
    for (int tile = 0; tile < 4; ++tile) {
        long e = blockBase + wv * 64 + tile * 16 + r;
        long ecl = (e < E) ? e : (long)(E - 1);
        int si = ei[ecl];
        int ti = ei[(long)E + ecl];

        // A fragments: af0/af1 = min(lo/hi halves), af2/af3 = max(lo/hi halves)
        union { short8 s; u32x4 u; } af0, af1, af2, af3;
        if (XMODE == 1) {
            const u32x4* ps = (const u32x4*)(xb + (long)si * LAT);
            const u32x4* pt = (const u32x4*)(xb + (long)ti * LAT);
            u32x4 sl = ps[g], sh = ps[4 + g];
            u32x4 tl = pt[g], th = pt[4 + g];
            #pragma unroll
            for (int q = 0; q < 4; ++q) {
                unsigned mn, mx;
                mnmx_word(sl[q], tl[q], mn, mx);
                af0.u[q] = mn; af2.u[q] = mx;
                mnmx_word(sh[q], th[q], mn, mx);
                af1.u[q] = mn; af3.u[q] = mx;
            }
        } else {
            const float4* ps = (const float4*)(xf + (long)si * LAT);
            const float4* pt = (const float4*)(xf + (long)ti * LAT);
            float4 sa = ps[2 * g], sb = ps[2 * g + 1], sc = ps[8 + 2 * g], sd = ps[9 + 2 * g];
            float4 ta = pt[2 * g], tb = pt[2 * g + 1], tc = pt[8 + 2 * g], td = pt[9 + 2 * g];
            MnMx4 m0 = mnmx4(sa, ta);
            MnMx4 m1 = mnmx4(sb, tb);
            MnMx4 m2 = mnmx4(sc, tc);
            MnMx4 m3 = mnmx4(sd, td);
            af0.u[0] = m0.w0; af0.u[1] = m0.w1; af2.u[0] = m0.x0; af2.u[1] = m0.x1;
            af0.u[2] = m1.w0; af0.u[3] = m1.w1; af2.u[2] = m1.x0; af2.u[3] = m1.x1;
            af1.u[0] = m2.w0; af1.u[1] = m2.w1; af3.u[0] = m2.x0; af3.u[1] = m2.x1;
            af1.u[2] = m3.w0; af1.u[3] = m3.w1; af3.u[2] = m3.x0; af3.u[3] = m3.x1;
        }

        // MFMA1: x_cat @ W1aug  (48 cols: 0-31 = W1, 32-35 = Wd, rest zero)
        f32x4 a0 = {0.f, 0.f, 0.f, 0.f}, a1 = a0, a2 = a0;
        a0 = __builtin_amdgcn_mfma_f32_16x16x32_bf16(af0.s, bfr[0],  a0, 0, 0, 0);
        a1 = __builtin_amdgcn_mfma_f32_16x16x32_bf16(af0.s, bfr[1],  a1, 0, 0, 0);
        a2 = __builtin_amdgcn_mfma_f32_16x16x32_bf16(af0.s, bfr[2],  a2, 0, 0, 0);
        a0 = __builtin_amdgcn_mfma_f32_16x16x32_bf16(af1.s, bfr[3],  a0, 0, 0, 0);
        a1 = __builtin_amdgcn_mfma_f32_16x16x32_bf16(af1.s, bfr[4],  a1, 0, 0, 0);
        a2 = __builtin_amdgcn_mfma_f32_16x16x32_bf16(af1.s, bfr[5],  a2, 0, 0, 0);
        a0 = __builtin_amdgcn_mfma_f32_16x16x32_bf16(af2.s, bfr[6],  a0, 0, 0, 0);
        a1 = __builtin_amdgcn_mfma_f32_16x16x32_bf16(af2.s, bfr[7],  a1, 0, 0, 0);
        a2 = __builtin_amdgcn_mfma_f32_16x16x32_bf16(af2.s, bfr[8],  a2, 0, 0, 0);
        a0 = __builtin_amdgcn_mfma_f32_16x16x32_bf16(af3.s, bfr[9],  a0, 0, 0, 0);
        a1 = __builtin_amdgcn_mfma_f32_16x16x32_bf16(af3.s, bfr[10], a1, 0, 0, 0);
        a2 = __builtin_amdgcn_mfma_f32_16x16x32_bf16(af3.s, bfr[11], a2, 0, 0, 0);

        // C/D layout (verified m89): col = lane&15, row = (lane>>4)*4 + reg
        const int rowbase = wv * 64 + tile * 16 + g * 4;
        // h1 = relu(. + b1), packed (feat r | feat r+16) per word
        #pragma unroll
        for (int p = 0; p < 4; ++p)
            hw[rowbase + p][r] = pk2(fmaxf(a0[p] + b1lo, 0.0f), fmaxf(a1[p] + b1hi, 0.0f));
        if (r < 4) {
            #pragma unroll
            for (int p = 0; p < 4; ++p) dls[rowbase + p][r] = a2[p];
        }

        // A-frag for MFMA2: lane reads edge (tile,r)'s words 4g..4g+3.
        // k-slot sigma(g,2q+h) = 4g+q+16h, matching fr2's build.
        // RAW within the same wave; ordered by the data dependence through MFMA2.
        union { short8 s; u32x4 u; } hf;
        const int erow = wv * 64 + tile * 16 + r;
        #pragma unroll
        for (int j = 0; j < 4; ++j) hf.u[j] = hw[erow][g * 4 + j];

        // MFMA2: h1 @ (W2 + I)  -> residual block in one GEMM
        f32x4 d0 = {0.f, 0.f, 0.f, 0.f}, d1 = d0;
        d0 = __builtin_amdgcn_mfma_f32_16x16x32_bf16(hf.s, w2f[0], d0, 0, 0, 0);
        d1 = __builtin_amdgcn_mfma_f32_16x16x32_bf16(hf.s, w2f[1], d1, 0, 0, 0);

        // h2 = relu(. + b2), overwrite h1 words (WAR safe: write depends on MFMA2 output)
        #pragma unroll
        for (int p = 0; p < 4; ++p)
            hw[rowbase + p][r] = pk2(fmaxf(d0[p] + b2lo, 0.0f), fmaxf(d1[p] + b2hi, 0.0f));
    }

    // ---- per-thread tail: out = h2 @ W3 + b3 + direct ----
    // No barrier: thread tid reads row tid, written by its own wave (wv = tid>>6).
    float o0 = b3[0] + bd[0] + dls[tid][0];
    float o1 = b3[1] + bd[1] + dls[tid][1];
    float o2 = b3[2] + bd[2] + dls[tid][2];
    float o3 = b3[3] + bd[3] + dls[tid][3];
    #pragma unroll
    for (int i = 0; i < 16; ++i) {
        unsigned w = hw[tid][i];
        float lo = __uint_as_float(w << 16);          // feat i
        float hi = __uint_as_float(w & 0xFFFF0000u);  // feat i+16
        const float* __restrict__ w3a = W3 + i * 4;
        const float* __restrict__ w3b = W3 + (i + 16) * 4;
        o0 = fmaf(lo, w3a[0], o0); o1 = fmaf(lo, w3a[1], o1);
        o2 = fmaf(lo, w3a[2], o2); o3 = fmaf(lo, w3a[3], o3);
        o0 = fmaf(hi, w3b[0], o0); o1 = fmaf(hi, w3b[1], o1);
        o2 = fmaf(hi, w3b[2], o2); o3 = fmaf(hi, w3b[3], o3);
    }
    long e = blockBase + tid;
    if (e < E) *(float4*)(out + e * 4) = make_float4(o0, o1, o2, o3);
}

// ---------- fallback (tiny ws): per-thread fp32 kernel ----------
__global__ __launch_bounds__(256) void edge_pred_fp32_kernel(
    const float* __restrict__ x, const int* __restrict__ ei,
    const float* __restrict__ Wd, const float* __restrict__ bd,
    const float* __restrict__ W1, const float* __restrict__ b1,
    const float* __restrict__ W2, const float* __restrict__ b2,
    const float* __restrict__ W3, const float* __restrict__ b3,
    float* __restrict__ out, int E)
{
    int e = blockIdx.x * blockDim.x + threadIdx.x;
    if (e >= E) return;
    int s = ei[e];
    int t = ei[E + e];
    const float4* xs4 = (const float4*)(x + (long)s * 64);
    const float4* xt4 = (const float4*)(x + (long)t * 64);
    float h[HID];
    #pragma unroll
    for (int j = 0; j < HID; ++j) h[j] = b1[j];
    float d0 = bd[0], d1 = bd[1], d2 = bd[2], d3 = bd[3];
    #pragma unroll 2
    for (int c = 0; c < 16; ++c) {
        float4 a = xs4[c];
        float4 b = xt4[c];
        float mn[4] = {fminf(a.x,b.x), fminf(a.y,b.y), fminf(a.z,b.z), fminf(a.w,b.w)};
        float mx[4] = {fmaxf(a.x,b.x), fmaxf(a.y,b.y), fmaxf(a.z,b.z), fmaxf(a.w,b.w)};
        #pragma unroll
        for (int q = 0; q < 4; ++q) {
            int lidx = c * 4 + q;
            const float* wlo = W1 + lidx * HID;
            const float* whi = W1 + (64 + lidx) * HID;
            #pragma unroll
            for (int j = 0; j < HID; ++j) { h[j] += mn[q]*wlo[j]; h[j] += mx[q]*whi[j]; }
            const float* dlo = Wd + lidx * 4;
            const float* dhi = Wd + (64 + lidx) * 4;
            d0 += mn[q]*dlo[0] + mx[q]*dhi[0];
            d1 += mn[q]*dlo[1] + mx[q]*dhi[1];
            d2 += mn[q]*dlo[2] + mx[q]*dhi[2];
            d3 += mn[q]*dlo[3] + mx[q]*dhi[3];
        }
    }
    float h1[HID];
    #pragma unroll
    for (int j = 0; j < HID; ++j) h1[j] = fmaxf(h[j], 0.0f);
    float s2[HID];
    #pragma unroll
    for (int j = 0; j < HID; ++j) s2[j] = b2[j] + h1[j];
    #pragma unroll 4
    for (int k = 0; k < HID; ++k) {
        const float* w2r = W2 + k * HID;
        #pragma unroll
        for (int j = 0; j < HID; ++j) s2[j] += h1[k] * w2r[j];
    }
    float o0 = b3[0] + d0, o1 = b3[1] + d1, o2 = b3[2] + d2, o3 = b3[3] + d3;
    #pragma unroll
    for (int k = 0; k < HID; ++k) {
        float hk = fmaxf(s2[k], 0.0f);
        const float* w3r = W3 + k * 4;
        o0 += hk*w3r[0]; o1 += hk*w3r[1]; o2 += hk*w3r[2]; o3 += hk*w3r[3];
    }
    *(float4*)(out + (long)e * 4) = make_float4(o0, o1, o2, o3);
}

extern "C" void kernel_launch(void* const* d_in, const int* in_sizes, int n_in,
                              void* d_out, int out_size, void* d_ws, size_t ws_size,
                              hipStream_t stream) {
    const float* x  = (const float*)d_in[0];
    const int*   ei = (const int*)d_in[1];
    const float* Wd = (const float*)d_in[2];
    const float* bd = (const float*)d_in[3];
    const float* W1 = (const float*)d_in[4];
    const float* b1 = (const float*)d_in[5];
    const float* W2 = (const float*)d_in[6];
    const float* b2 = (const float*)d_in[7];
    const float* W3 = (const float*)d_in[8];
    const float* b3 = (const float*)d_in[9];
    float* out = (float*)d_out;

    int E  = in_sizes[1] / 2;
    int NN = in_sizes[0] / LAT;

    size_t fbytes  = (size_t)NFRAG  * 64 * 16;   // 12 KB W1aug frags
    size_t f2bytes = (size_t)NFRAG2 * 64 * 16;   // 2 KB  W2aug frags
    size_t fpad    = (fbytes + f2bytes + 255) & ~(size_t)255;
    size_t xbytes  = (size_t)NN * LAT * 2;       // bf16 x

    int grid = (E + EPB - 1) / EPB;
    if (ws_size >= fpad + xbytes) {
        unsigned short* frg  = (unsigned short*)d_ws;
        unsigned short* frg2 = (unsigned short*)((char*)d_ws + fbytes);
        unsigned short* xb   = (unsigned short*)((char*)d_ws + fpad);
        hipLaunchKernelGGL(build_frags_kernel, dim3(4), dim3(256), 0, stream, W1, Wd, W2, frg, frg2);
        int n8 = NN * LAT / 8;
        hipLaunchKernelGGL(cvt_x_kernel, dim3((n8 + 255) / 256), dim3(256), 0, stream, x, xb, n8);
        hipLaunchKernelGGL((edge_mfma_kernel<1>), dim3(grid), dim3(256), 0, stream,
                           x, xb, frg, frg2, ei, b1, bd, b2, W3, b3, out, E);
    } else if (ws_size >= fbytes + f2bytes) {
        unsigned short* frg  = (unsigned short*)d_ws;
        unsigned short* frg2 = (unsigned short*)((char*)d_ws + fbytes);
        hipLaunchKernelGGL(build_frags_kernel, dim3(4), dim3(256), 0, stream, W1, Wd, W2, frg, frg2);
        hipLaunchKernelGGL((edge_mfma_kernel<0>), dim3(grid), dim3(256), 0, stream,
                           x, (const unsigned short*)nullptr, frg, frg2, ei, b1, bd, b2, W3, b3, out, E);
    } else {
        hipLaunchKernelGGL(edge_pred_fp32_kernel, dim3((E + 255) / 256), dim3(256), 0, stream,
                           x, ei, Wd, bd, W1, b1, W2, b2, W3, b3, out, E);
    }
}

// Round 5
// 83.402 us; speedup vs baseline: 4.1245x; 1.0475x over previous
//
#include <hip/hip_runtime.h>

typedef __attribute__((ext_vector_type(8))) short short8;       // 8 x bf16 (4 VGPR)
typedef __attribute__((ext_vector_type(4))) float f32x4;         // MFMA acc
typedef __attribute__((ext_vector_type(4))) unsigned int u32x4;

constexpr int HID = 32;
constexpr int LAT = 64;    // latent dim
constexpr int EPB = 256;   // edges per block (4 waves x 4 tiles x 16 edges)
constexpr int NFRAG  = 12; // W1aug [128 x 48]: 4 k-steps x 3 N-tiles
constexpr int NFRAG2 = 2;  // W2aug [32 x 32]: 1 k-step x 2 N-tiles
constexpr int NFRAG3 = 1;  // W3aug [32 x 16]: 1 k-step x 1 N-tile (cols 0-3 = W3)
constexpr int HW_STRIDE = 17; // u32 words per edge row (16 feat-pairs + 1 pad)

// ---------- helpers ----------
// Single-instruction packed f32->2xbf16 RNE (T12: no builtin on gfx950).
__device__ __forceinline__ unsigned pk2(float lo, float hi) {
    unsigned r;
    asm("v_cvt_pk_bf16_f32 %0, %1, %2" : "=v"(r) : "v"(lo), "v"(hi));
    return r;
}
// packed-bf16-pair min/max (inputs exact bf16 -> cvt_pk repack is exact)
__device__ __forceinline__ void mnmx_word(unsigned a, unsigned b, unsigned& mn, unsigned& mx) {
    float al = __uint_as_float(a << 16), ah = __uint_as_float(a & 0xFFFF0000u);
    float bl = __uint_as_float(b << 16), bh = __uint_as_float(b & 0xFFFF0000u);
    mn = pk2(fminf(al, bl), fminf(ah, bh));
    mx = pk2(fmaxf(al, bl), fmaxf(ah, bh));
}
struct MnMx4 { unsigned w0, w1, x0, x1; };
__device__ __forceinline__ MnMx4 mnmx4(float4 a, float4 b) {
    MnMx4 r;
    r.w0 = pk2(fminf(a.x, b.x), fminf(a.y, b.y));
    r.w1 = pk2(fminf(a.z, b.z), fminf(a.w, b.w));
    r.x0 = pk2(fmaxf(a.x, b.x), fmaxf(a.y, b.y));
    r.x1 = pk2(fmaxf(a.z, b.z), fmaxf(a.w, b.w));
    return r;
}

// ---------- pre-pass: x fp32 -> bf16 ----------
__global__ __launch_bounds__(256) void cvt_x_kernel(const float* __restrict__ x,
                                                    unsigned short* __restrict__ xb, int n8) {
    int i = blockIdx.x * blockDim.x + threadIdx.x;
    if (i >= n8) return;
    const float4* p = (const float4*)x + (long)i * 2;
    float4 a = p[0], b = p[1];
    u32x4 v = { pk2(a.x, a.y), pk2(a.z, a.w), pk2(b.x, b.y), pk2(b.z, b.w) };
    ((u32x4*)xb)[i] = v;
}

// ---------- pre-pass: build B-fragments ----------
// W1aug frags: frag ft = s*3+t. Lane l holds B[k=s*32+(l>>4)*8+i][col 16t+(l&15)],
//   i=0..7 packed bf16x8. Tile 2: cols 0-3 = Wd, 4-15 = zero.
// W2aug frags: W2+I, k-slot sigma(g, 2q+h) = 4g+q+16h (matches A-pack of h-words).
// W3aug frag: same sigma, cols 0-3 = W3, 4-15 = zero.
__global__ __launch_bounds__(256) void build_frags_kernel(const float* __restrict__ W1,
                                                          const float* __restrict__ Wd,
                                                          const float* __restrict__ W2,
                                                          const float* __restrict__ W3,
                                                          unsigned short* __restrict__ fr,
                                                          unsigned short* __restrict__ fr2,
                                                          unsigned short* __restrict__ fr3) {
    int id = blockIdx.x * blockDim.x + threadIdx.x;
    if (id < NFRAG * 64) {
        int l = id & 63;
        int ft = id >> 6;
        int s = ft / 3, t = ft - s * 3;
        int g = l >> 4, c = l & 15;
        unsigned w[4];
        #pragma unroll
        for (int q = 0; q < 4; ++q) {
            int k = s * 32 + g * 8 + q * 2;
            float lo, hi;
            if (t < 2) { lo = W1[k * HID + t * 16 + c]; hi = W1[(k + 1) * HID + t * 16 + c]; }
            else { lo = (c < 4) ? Wd[k * 4 + c] : 0.0f; hi = (c < 4) ? Wd[(k + 1) * 4 + c] : 0.0f; }
            w[q] = pk2(lo, hi);
        }
        u32x4 v = { w[0], w[1], w[2], w[3] };
        ((u32x4*)fr)[ft * 64 + l] = v;
    } else if (id < (NFRAG + NFRAG2) * 64) {
        int f2 = id - NFRAG * 64;
        int l = f2 & 63;
        int t = f2 >> 6;
        int g = l >> 4, c = l & 15;
        int col = t * 16 + c;
        unsigned w[4];
        #pragma unroll
        for (int q = 0; q < 4; ++q) {
            int f0 = g * 4 + q;       // k-slot 2q   -> feature f0
            int f1 = f0 + 16;         // k-slot 2q+1 -> feature f0+16
            float lo = W2[f0 * HID + col] + (f0 == col ? 1.0f : 0.0f);
            float hi = W2[f1 * HID + col] + (f1 == col ? 1.0f : 0.0f);
            w[q] = pk2(lo, hi);
        }
        u32x4 v = { w[0], w[1], w[2], w[3] };
        ((u32x4*)fr2)[t * 64 + l] = v;
    } else if (id < (NFRAG + NFRAG2 + NFRAG3) * 64) {
        int l = id - (NFRAG + NFRAG2) * 64;
        int g = l >> 4, c = l & 15;
        unsigned w[4];
        #pragma unroll
        for (int q = 0; q < 4; ++q) {
            int f0 = g * 4 + q;
            int f1 = f0 + 16;
            float lo = (c < 4) ? W3[f0 * 4 + c] : 0.0f;
            float hi = (c < 4) ? W3[f1 * 4 + c] : 0.0f;
            w[q] = pk2(lo, hi);
        }
        u32x4 v = { w[0], w[1], w[2], w[3] };
        ((u32x4*)fr3)[l] = v;
    }
}

// ---------- main kernel ----------
// XMODE 1: gather bf16 x from ws; XMODE 0: gather fp32 x directly.
template<int XMODE>
__global__ __launch_bounds__(256, 4) void edge_mfma_kernel(
    const float* __restrict__ xf,
    const unsigned short* __restrict__ xb,
    const unsigned short* __restrict__ fr,
    const unsigned short* __restrict__ fr2,
    const unsigned short* __restrict__ fr3,
    const int* __restrict__ ei,
    const float* __restrict__ b1, const float* __restrict__ bd,
    const float* __restrict__ b2, const float* __restrict__ b3,
    float* __restrict__ out, int E)
{
    __shared__ unsigned hw[EPB][HW_STRIDE];  // bf16-pair words: (feat r, feat r+16)
    __shared__ float4 ols[EPB];              // final outputs (transposed via LDS)
    const int tid = threadIdx.x;
    const int l = tid & 63;
    const int wv = tid >> 6;
    const int g = l >> 4, r = l & 15;
    const long blockBase = (long)blockIdx.x * EPB;

    // B-fragments resident in VGPRs (48 + 8 + 4)
    short8 bfr[NFRAG];
    #pragma unroll
    for (int f = 0; f < NFRAG; ++f) bfr[f] = ((const short8*)fr)[f * 64 + l];
    short8 w2f[NFRAG2];
    #pragma unroll
    for (int f = 0; f < NFRAG2; ++f) w2f[f] = ((const short8*)fr2)[f * 64 + l];
    short8 w3f = ((const short8*)fr3)[l];

    const float b1lo = b1[r], b1hi = b1[16 + r];
    const float b2lo = b2[r], b2hi = b2[16 + r];
    // C-init for the direct-path accumulator: bd[r]+b3[r] lands in cols r<4
    const float cinit = (r < 4) ? (bd[r] + b3[r]) : 0.0f;

    #pragma unroll
    for (int tile = 0; tile < 4; ++tile) {
        long e = blockBase + wv * 64 + tile * 16 + r;
        long ecl = (e < E) ? e : (long)(E - 1);
        int si = ei[ecl];
        int ti = ei[(long)E + ecl];

        // A fragments: af0/af1 = min(lo/hi halves), af2/af3 = max(lo/hi halves)
        union { short8 s; u32x4 u; } af0, af1, af2, af3;
        if (XMODE == 1) {
            const u32x4* ps = (const u32x4*)(xb + (long)si * LAT);
            const u32x4* pt = (const u32x4*)(xb + (long)ti * LAT);
            u32x4 sl = ps[g], sh = ps[4 + g];
            u32x4 tl = pt[g], th = pt[4 + g];
            #pragma unroll
            for (int q = 0; q < 4; ++q) {
                unsigned mn, mx;
                mnmx_word(sl[q], tl[q], mn, mx);
                af0.u[q] = mn; af2.u[q] = mx;
                mnmx_word(sh[q], th[q], mn, mx);
                af1.u[q] = mn; af3.u[q] = mx;
            }
        } else {
            const float4* ps = (const float4*)(xf + (long)si * LAT);
            const float4* pt = (const float4*)(xf + (long)ti * LAT);
            float4 sa = ps[2 * g], sb = ps[2 * g + 1], sc = ps[8 + 2 * g], sd = ps[9 + 2 * g];
            float4 ta = pt[2 * g], tb = pt[2 * g + 1], tc = pt[8 + 2 * g], td = pt[9 + 2 * g];
            MnMx4 m0 = mnmx4(sa, ta);
            MnMx4 m1 = mnmx4(sb, tb);
            MnMx4 m2 = mnmx4(sc, tc);
            MnMx4 m3 = mnmx4(sd, td);
            af0.u[0] = m0.w0; af0.u[1] = m0.w1; af2.u[0] = m0.x0; af2.u[1] = m0.x1;
            af0.u[2] = m1.w0; af0.u[3] = m1.w1; af2.u[2] = m1.x0; af2.u[3] = m1.x1;
            af1.u[0] = m2.w0; af1.u[1] = m2.w1; af3.u[0] = m2.x0; af3.u[1] = m2.x1;
            af1.u[2] = m3.w0; af1.u[3] = m3.w1; af3.u[2] = m3.x0; af3.u[3] = m3.x1;
        }

        // MFMA1: x_cat @ W1aug  (48 cols: 0-31 = W1 -> a0,a1; 32-35 = Wd -> a2)
        f32x4 a0 = {0.f, 0.f, 0.f, 0.f}, a1 = a0;
        f32x4 a2 = {cinit, cinit, cinit, cinit};
        a0 = __builtin_amdgcn_mfma_f32_16x16x32_bf16(af0.s, bfr[0],  a0, 0, 0, 0);
        a1 = __builtin_amdgcn_mfma_f32_16x16x32_bf16(af0.s, bfr[1],  a1, 0, 0, 0);
        a2 = __builtin_amdgcn_mfma_f32_16x16x32_bf16(af0.s, bfr[2],  a2, 0, 0, 0);
        a0 = __builtin_amdgcn_mfma_f32_16x16x32_bf16(af1.s, bfr[3],  a0, 0, 0, 0);
        a1 = __builtin_amdgcn_mfma_f32_16x16x32_bf16(af1.s, bfr[4],  a1, 0, 0, 0);
        a2 = __builtin_amdgcn_mfma_f32_16x16x32_bf16(af1.s, bfr[5],  a2, 0, 0, 0);
        a0 = __builtin_amdgcn_mfma_f32_16x16x32_bf16(af2.s, bfr[6],  a0, 0, 0, 0);
        a1 = __builtin_amdgcn_mfma_f32_16x16x32_bf16(af2.s, bfr[7],  a1, 0, 0, 0);
        a2 = __builtin_amdgcn_mfma_f32_16x16x32_bf16(af2.s, bfr[8],  a2, 0, 0, 0);
        a0 = __builtin_amdgcn_mfma_f32_16x16x32_bf16(af3.s, bfr[9],  a0, 0, 0, 0);
        a1 = __builtin_amdgcn_mfma_f32_16x16x32_bf16(af3.s, bfr[10], a1, 0, 0, 0);
        a2 = __builtin_amdgcn_mfma_f32_16x16x32_bf16(af3.s, bfr[11], a2, 0, 0, 0);

        // C/D layout (verified m89): col = lane&15, row = (lane>>4)*4 + reg
        const int rowbase = wv * 64 + tile * 16 + g * 4;
        const int erow = wv * 64 + tile * 16 + r;

        // h1 = relu(. + b1), packed (feat r | feat r+16) per word
        #pragma unroll
        for (int p = 0; p < 4; ++p)
            hw[rowbase + p][r] = pk2(fmaxf(a0[p] + b1lo, 0.0f), fmaxf(a1[p] + b1hi, 0.0f));

        // A-frag for MFMA2: lane reads edge (tile,r)'s words 4g..4g+3.
        // Cross-lane RAW within the same wave; DS pipe executes a wave's LDS
        // ops in order, and may-alias indices stop compiler reordering.
        union { short8 s; u32x4 u; } hf;
        #pragma unroll
        for (int j = 0; j < 4; ++j) hf.u[j] = hw[erow][g * 4 + j];

        // MFMA2: h1 @ (W2 + I)  -> residual block in one GEMM
        f32x4 d0 = {0.f, 0.f, 0.f, 0.f}, d1 = d0;
        d0 = __builtin_amdgcn_mfma_f32_16x16x32_bf16(hf.s, w2f[0], d0, 0, 0, 0);
        d1 = __builtin_amdgcn_mfma_f32_16x16x32_bf16(hf.s, w2f[1], d1, 0, 0, 0);

        // h2 = relu(. + b2), overwrite h1 words in place
        #pragma unroll
        for (int p = 0; p < 4; ++p)
            hw[rowbase + p][r] = pk2(fmaxf(d0[p] + b2lo, 0.0f), fmaxf(d1[p] + b2hi, 0.0f));

        // A-frag for MFMA3: re-read h2 words (same pattern as MFMA2's A)
        union { short8 s; u32x4 u; } hf2;
        #pragma unroll
        for (int j = 0; j < 4; ++j) hf2.u[j] = hw[erow][g * 4 + j];

        // MFMA3: out_tile = h2 @ W3aug + a2 (a2's D layout == this C layout:
        // row = edge, col = channel; a2 already holds dp + bd + b3 in cols 0-3)
        f32x4 d3 = __builtin_amdgcn_mfma_f32_16x16x32_bf16(hf2.s, w3f, a2, 0, 0, 0);

        // transpose to edge-major via LDS (only cols 0-3 are real)
        if (r < 4) {
            #pragma unroll
            for (int p = 0; p < 4; ++p) ((float*)&ols[rowbase + p])[r] = d3[p];
        }
    }

    // No barrier: thread tid reads row tid, written by its own wave (wv = tid>>6).
    long e = blockBase + tid;
    if (e < E) ((float4*)out)[e] = ols[tid];
}

// ---------- fallback (tiny ws): per-thread fp32 kernel ----------
__global__ __launch_bounds__(256) void edge_pred_fp32_kernel(
    const float* __restrict__ x, const int* __restrict__ ei,
    const float* __restrict__ Wd, const float* __restrict__ bd,
    const float* __restrict__ W1, const float* __restrict__ b1,
    const float* __restrict__ W2, const float* __restrict__ b2,
    const float* __restrict__ W3, const float* __restrict__ b3,
    float* __restrict__ out, int E)
{
    int e = blockIdx.x * blockDim.x + threadIdx.x;
    if (e >= E) return;
    int s = ei[e];
    int t = ei[E + e];
    const float4* xs4 = (const float4*)(x + (long)s * 64);
    const float4* xt4 = (const float4*)(x + (long)t * 64);
    float h[HID];
    #pragma unroll
    for (int j = 0; j < HID; ++j) h[j] = b1[j];
    float d0 = bd[0], d1 = bd[1], d2 = bd[2], d3 = bd[3];
    #pragma unroll 2
    for (int c = 0; c < 16; ++c) {
        float4 a = xs4[c];
        float4 b = xt4[c];
        float mn[4] = {fminf(a.x,b.x), fminf(a.y,b.y), fminf(a.z,b.z), fminf(a.w,b.w)};
        float mx[4] = {fmaxf(a.x,b.x), fmaxf(a.y,b.y), fmaxf(a.z,b.z), fmaxf(a.w,b.w)};
        #pragma unroll
        for (int q = 0; q < 4; ++q) {
            int lidx = c * 4 + q;
            const float* wlo = W1 + lidx * HID;
            const float* whi = W1 + (64 + lidx) * HID;
            #pragma unroll
            for (int j = 0; j < HID; ++j) { h[j] += mn[q]*wlo[j]; h[j] += mx[q]*whi[j]; }
            const float* dlo = Wd + lidx * 4;
            const float* dhi = Wd + (64 + lidx) * 4;
            d0 += mn[q]*dlo[0] + mx[q]*dhi[0];
            d1 += mn[q]*dlo[1] + mx[q]*dhi[1];
            d2 += mn[q]*dlo[2] + mx[q]*dhi[2];
            d3 += mn[q]*dlo[3] + mx[q]*dhi[3];
        }
    }
    float h1[HID];
    #pragma unroll
    for (int j = 0; j < HID; ++j) h1[j] = fmaxf(h[j], 0.0f);
    float s2[HID];
    #pragma unroll
    for (int j = 0; j < HID; ++j) s2[j] = b2[j] + h1[j];
    #pragma unroll 4
    for (int k = 0; k < HID; ++k) {
        const float* w2r = W2 + k * HID;
        #pragma unroll
        for (int j = 0; j < HID; ++j) s2[j] += h1[k] * w2r[j];
    }
    float o0 = b3[0] + d0, o1 = b3[1] + d1, o2 = b3[2] + d2, o3 = b3[3] + d3;
    #pragma unroll
    for (int k = 0; k < HID; ++k) {
        float hk = fmaxf(s2[k], 0.0f);
        const float* w3r = W3 + k * 4;
        o0 += hk*w3r[0]; o1 += hk*w3r[1]; o2 += hk*w3r[2]; o3 += hk*w3r[3];
    }
    *(float4*)(out + (long)e * 4) = make_float4(o0, o1, o2, o3);
}

extern "C" void kernel_launch(void* const* d_in, const int* in_sizes, int n_in,
                              void* d_out, int out_size, void* d_ws, size_t ws_size,
                              hipStream_t stream) {
    const float* x  = (const float*)d_in[0];
    const int*   ei = (const int*)d_in[1];
    const float* Wd = (const float*)d_in[2];
    const float* bd = (const float*)d_in[3];
    const float* W1 = (const float*)d_in[4];
    const float* b1 = (const float*)d_in[5];
    const float* W2 = (const float*)d_in[6];
    const float* b2 = (const float*)d_in[7];
    const float* W3 = (const float*)d_in[8];
    const float* b3 = (const float*)d_in[9];
    float* out = (float*)d_out;

    int E  = in_sizes[1] / 2;
    int NN = in_sizes[0] / LAT;

    size_t fbytes  = (size_t)NFRAG  * 64 * 16;   // 12 KB W1aug frags
    size_t f2bytes = (size_t)NFRAG2 * 64 * 16;   // 2 KB  W2aug frags
    size_t f3bytes = (size_t)NFRAG3 * 64 * 16;   // 1 KB  W3aug frag
    size_t fall    = fbytes + f2bytes + f3bytes;
    size_t fpad    = (fall + 255) & ~(size_t)255;
    size_t xbytes  = (size_t)NN * LAT * 2;       // bf16 x

    int grid = (E + EPB - 1) / EPB;
    if (ws_size >= fpad + xbytes) {
        unsigned short* frg  = (unsigned short*)d_ws;
        unsigned short* frg2 = (unsigned short*)((char*)d_ws + fbytes);
        unsigned short* frg3 = (unsigned short*)((char*)d_ws + fbytes + f2bytes);
        unsigned short* xb   = (unsigned short*)((char*)d_ws + fpad);
        hipLaunchKernelGGL(build_frags_kernel, dim3(4), dim3(256), 0, stream,
                           W1, Wd, W2, W3, frg, frg2, frg3);
        int n8 = NN * LAT / 8;
        hipLaunchKernelGGL(cvt_x_kernel, dim3((n8 + 255) / 256), dim3(256), 0, stream, x, xb, n8);
        hipLaunchKernelGGL((edge_mfma_kernel<1>), dim3(grid), dim3(256), 0, stream,
                           x, xb, frg, frg2, frg3, ei, b1, bd, b2, b3, out, E);
    } else if (ws_size >= fall) {
        unsigned short* frg  = (unsigned short*)d_ws;
        unsigned short* frg2 = (unsigned short*)((char*)d_ws + fbytes);
        unsigned short* frg3 = (unsigned short*)((char*)d_ws + fbytes + f2bytes);
        hipLaunchKernelGGL(build_frags_kernel, dim3(4), dim3(256), 0, stream,
                           W1, Wd, W2, W3, frg, frg2, frg3);
        hipLaunchKernelGGL((edge_mfma_kernel<0>), dim3(grid), dim3(256), 0, stream,
                           x, (const unsigned short*)nullptr, frg, frg2, frg3,
                           ei, b1, bd, b2, b3, out, E);
    } else {
        hipLaunchKernelGGL(edge_pred_fp32_kernel, dim3((E + 255) / 256), dim3(256), 0, stream,
                           x, ei, Wd, bd, W1, b1, W2, b2, W3, b3, out, E);
    }
}

// Round 6
// 77.742 us; speedup vs baseline: 4.4249x; 1.0728x over previous
//
#include <hip/hip_runtime.h>

typedef __attribute__((ext_vector_type(8))) short short8;       // 8 x bf16 (4 VGPR)
typedef __attribute__((ext_vector_type(4))) float f32x4;         // MFMA acc
typedef __attribute__((ext_vector_type(4))) unsigned int u32x4;

constexpr int HID = 32;
constexpr int LAT = 64;    // latent dim
constexpr int EPB = 256;   // edges per block (4 waves x 4 tiles x 16 edges)
constexpr int NFRAG  = 12; // W1aug^T [128 x 48]: 4 k-steps x 3 N-tiles
constexpr int NFRAG2 = 2;  // W2aug^T [32 x 32]: 2 tiles, sigma' k-order
constexpr int NFRAG3 = 1;  // W3aug^T [32 x 16]: rows(c)<4 real

// ---------- helpers ----------
__device__ __forceinline__ unsigned pk2(float lo, float hi) {
    unsigned r;
    asm("v_cvt_pk_bf16_f32 %0, %1, %2" : "=v"(r) : "v"(lo), "v"(hi));
    return r;
}
// packed-bf16-pair min/max (inputs exact bf16 -> cvt_pk repack is exact)
__device__ __forceinline__ void mnmx_word(unsigned a, unsigned b, unsigned& mn, unsigned& mx) {
    float al = __uint_as_float(a << 16), ah = __uint_as_float(a & 0xFFFF0000u);
    float bl = __uint_as_float(b << 16), bh = __uint_as_float(b & 0xFFFF0000u);
    mn = pk2(fminf(al, bl), fminf(ah, bh));
    mx = pk2(fmaxf(al, bl), fmaxf(ah, bh));
}
struct MnMx4 { unsigned w0, w1, x0, x1; };
__device__ __forceinline__ MnMx4 mnmx4(float4 a, float4 b) {
    MnMx4 r;
    r.w0 = pk2(fminf(a.x, b.x), fminf(a.y, b.y));
    r.w1 = pk2(fminf(a.z, b.z), fminf(a.w, b.w));
    r.x0 = pk2(fmaxf(a.x, b.x), fmaxf(a.y, b.y));
    r.x1 = pk2(fmaxf(a.z, b.z), fmaxf(a.w, b.w));
    return r;
}

// ---------- merged prep: build frags (blocks 0-3) + x fp32->bf16 (blocks 4+) ----------
// W1aug^T frags (contents identical to B-form; role swap happens at the mfma call):
//   frag ft = s*3+t, lane l=(g,c): word q = (W1aug[s*32+8g+2q][16t+c], W1aug[s*32+8g+2q+1][16t+c])
//   tile 2 cols: 0-3 = Wd, 4-15 = zero.
// W2aug^T frags (sigma' k-order matching in-lane h packing: i<4 -> 4g+i, else 16+4g+i-4):
//   word q: kbase = q<2 ? 4g+2q : 16+4g+2(q-2); (W2aug[kbase][col], W2aug[kbase+1][col]), W2aug = W2+I.
// W3aug^T frag: same sigma'; value = (c<4) ? W3[k][c] : 0.
__global__ __launch_bounds__(256) void prep_kernel(const float* __restrict__ x,
                                                   const float* __restrict__ W1,
                                                   const float* __restrict__ Wd,
                                                   const float* __restrict__ W2,
                                                   const float* __restrict__ W3,
                                                   unsigned short* __restrict__ fr,
                                                   unsigned short* __restrict__ fr2,
                                                   unsigned short* __restrict__ fr3,
                                                   unsigned short* __restrict__ xb, int n8) {
    if (blockIdx.x < 4) {
        int id = blockIdx.x * 256 + threadIdx.x;
        if (id < NFRAG * 64) {
            int l = id & 63;
            int ft = id >> 6;
            int s = ft / 3, t = ft - s * 3;
            int g = l >> 4, c = l & 15;
            unsigned w[4];
            #pragma unroll
            for (int q = 0; q < 4; ++q) {
                int k = s * 32 + g * 8 + q * 2;
                float lo, hi;
                if (t < 2) { lo = W1[k * HID + t * 16 + c]; hi = W1[(k + 1) * HID + t * 16 + c]; }
                else { lo = (c < 4) ? Wd[k * 4 + c] : 0.0f; hi = (c < 4) ? Wd[(k + 1) * 4 + c] : 0.0f; }
                w[q] = pk2(lo, hi);
            }
            u32x4 v = { w[0], w[1], w[2], w[3] };
            ((u32x4*)fr)[ft * 64 + l] = v;
        } else if (id < (NFRAG + NFRAG2) * 64) {
            int f2 = id - NFRAG * 64;
            int l = f2 & 63;
            int t = f2 >> 6;
            int g = l >> 4, c = l & 15;
            int col = t * 16 + c;
            unsigned w[4];
            #pragma unroll
            for (int q = 0; q < 4; ++q) {
                int kb = (q < 2) ? (g * 4 + 2 * q) : (16 + g * 4 + 2 * (q - 2));
                float lo = W2[kb * HID + col] + (kb == col ? 1.0f : 0.0f);
                float hi = W2[(kb + 1) * HID + col] + ((kb + 1) == col ? 1.0f : 0.0f);
                w[q] = pk2(lo, hi);
            }
            u32x4 v = { w[0], w[1], w[2], w[3] };
            ((u32x4*)fr2)[t * 64 + l] = v;
        } else if (id < (NFRAG + NFRAG2 + NFRAG3) * 64) {
            int l = id - (NFRAG + NFRAG2) * 64;
            int g = l >> 4, c = l & 15;
            unsigned w[4];
            #pragma unroll
            for (int q = 0; q < 4; ++q) {
                int kb = (q < 2) ? (g * 4 + 2 * q) : (16 + g * 4 + 2 * (q - 2));
                float lo = (c < 4) ? W3[kb * 4 + c] : 0.0f;
                float hi = (c < 4) ? W3[(kb + 1) * 4 + c] : 0.0f;
                w[q] = pk2(lo, hi);
            }
            u32x4 v = { w[0], w[1], w[2], w[3] };
            ((u32x4*)fr3)[l] = v;
        }
    } else {
        int i = (blockIdx.x - 4) * 256 + threadIdx.x;
        if (i < n8) {
            const float4* p = (const float4*)x + (long)i * 2;
            float4 a = p[0], b = p[1];
            u32x4 v = { pk2(a.x, a.y), pk2(a.z, a.w), pk2(b.x, b.y), pk2(b.z, b.w) };
            ((u32x4*)xb)[i] = v;
        }
    }
}

// ---------- main kernel: weights-as-A, edges-as-B -> zero LDS ----------
// XMODE 1: gather bf16 x from ws; XMODE 0: gather fp32 x directly.
template<int XMODE>
__global__ __launch_bounds__(256, 2) void edge_mfma_kernel(
    const float* __restrict__ xf,
    const unsigned short* __restrict__ xb,
    const unsigned short* __restrict__ fr,
    const unsigned short* __restrict__ fr2,
    const unsigned short* __restrict__ fr3,
    const int* __restrict__ ei,
    const float* __restrict__ b1, const float* __restrict__ bd,
    const float* __restrict__ b2, const float* __restrict__ b3,
    float* __restrict__ out, int E)
{
    const int tid = threadIdx.x;
    const int l = tid & 63;
    const int wv = tid >> 6;
    const int g = l >> 4, r = l & 15;
    const long waveBase = (long)blockIdx.x * EPB + wv * 64;

    // Weight A-fragments resident in VGPRs (48 + 8 + 4)
    short8 bfr[NFRAG];
    #pragma unroll
    for (int f = 0; f < NFRAG; ++f) bfr[f] = ((const short8*)fr)[f * 64 + l];
    short8 w2t[NFRAG2];
    #pragma unroll
    for (int f = 0; f < NFRAG2; ++f) w2t[f] = ((const short8*)fr2)[f * 64 + l];
    short8 w3t = ((const short8*)fr3)[l];

    // Biases for the out-feats this lane holds (rows 4g+p and 16+4g+p)
    const float4 b1a = ((const float4*)b1)[g], b1b = ((const float4*)b1)[4 + g];
    const float4 b2a = ((const float4*)b2)[g], b2b = ((const float4*)b2)[4 + g];
    // C-init for the direct-path mfma: channels live at local rows 0-3 (g==0)
    f32x4 a2init;
    #pragma unroll
    for (int p = 0; p < 4; ++p) a2init[p] = (g == 0) ? (bd[p] + b3[p]) : 0.0f;

    // Prologue: all 4 tiles' edge indices
    int sidx[4], tidx[4];
    #pragma unroll
    for (int t = 0; t < 4; ++t) {
        long e = waveBase + t * 16 + r;
        long ecl = (e < E) ? e : (long)(E - 1);
        sidx[t] = ei[ecl];
        tidx[t] = ei[(long)E + ecl];
    }

    // Per-tile compute: af* are B-fragments (lane holds edge r's x_cat k-slots).
    auto compute_tile = [&](short8 af0, short8 af1, short8 af2, short8 af3, int t) {
        f32x4 a0 = {0.f, 0.f, 0.f, 0.f}, a1 = a0;
        f32x4 a2 = a2init;
        a0 = __builtin_amdgcn_mfma_f32_16x16x32_bf16(bfr[0],  af0, a0, 0, 0, 0);
        a1 = __builtin_amdgcn_mfma_f32_16x16x32_bf16(bfr[1],  af0, a1, 0, 0, 0);
        a2 = __builtin_amdgcn_mfma_f32_16x16x32_bf16(bfr[2],  af0, a2, 0, 0, 0);
        a0 = __builtin_amdgcn_mfma_f32_16x16x32_bf16(bfr[3],  af1, a0, 0, 0, 0);
        a1 = __builtin_amdgcn_mfma_f32_16x16x32_bf16(bfr[4],  af1, a1, 0, 0, 0);
        a2 = __builtin_amdgcn_mfma_f32_16x16x32_bf16(bfr[5],  af1, a2, 0, 0, 0);
        a0 = __builtin_amdgcn_mfma_f32_16x16x32_bf16(bfr[6],  af2, a0, 0, 0, 0);
        a1 = __builtin_amdgcn_mfma_f32_16x16x32_bf16(bfr[7],  af2, a1, 0, 0, 0);
        a2 = __builtin_amdgcn_mfma_f32_16x16x32_bf16(bfr[8],  af2, a2, 0, 0, 0);
        a0 = __builtin_amdgcn_mfma_f32_16x16x32_bf16(bfr[9],  af3, a0, 0, 0, 0);
        a1 = __builtin_amdgcn_mfma_f32_16x16x32_bf16(bfr[10], af3, a1, 0, 0, 0);
        a2 = __builtin_amdgcn_mfma_f32_16x16x32_bf16(bfr[11], af3, a2, 0, 0, 0);

        // h1 = relu(. + b1): lane (g,r) holds edge r's feats {4g+p} (a0), {16+4g+p} (a1)
        // -> already the B-fragment layout for the next mfma (sigma' in fr2/fr3).
        union { short8 s; u32x4 u; } hf;
        hf.u[0] = pk2(fmaxf(a0[0] + b1a.x, 0.0f), fmaxf(a0[1] + b1a.y, 0.0f));
        hf.u[1] = pk2(fmaxf(a0[2] + b1a.z, 0.0f), fmaxf(a0[3] + b1a.w, 0.0f));
        hf.u[2] = pk2(fmaxf(a1[0] + b1b.x, 0.0f), fmaxf(a1[1] + b1b.y, 0.0f));
        hf.u[3] = pk2(fmaxf(a1[2] + b1b.z, 0.0f), fmaxf(a1[3] + b1b.w, 0.0f));

        f32x4 d0 = {0.f, 0.f, 0.f, 0.f}, d1 = d0;
        d0 = __builtin_amdgcn_mfma_f32_16x16x32_bf16(w2t[0], hf.s, d0, 0, 0, 0);
        d1 = __builtin_amdgcn_mfma_f32_16x16x32_bf16(w2t[1], hf.s, d1, 0, 0, 0);

        union { short8 s; u32x4 u; } hf2;
        hf2.u[0] = pk2(fmaxf(d0[0] + b2a.x, 0.0f), fmaxf(d0[1] + b2a.y, 0.0f));
        hf2.u[1] = pk2(fmaxf(d0[2] + b2a.z, 0.0f), fmaxf(d0[3] + b2a.w, 0.0f));
        hf2.u[2] = pk2(fmaxf(d1[0] + b2b.x, 0.0f), fmaxf(d1[1] + b2b.y, 0.0f));
        hf2.u[3] = pk2(fmaxf(d1[2] + b2b.z, 0.0f), fmaxf(d1[3] + b2b.w, 0.0f));

        // MFMA3: rows 0-3 = channels (lanes g==0), C carries direct path + biases
        f32x4 d3 = __builtin_amdgcn_mfma_f32_16x16x32_bf16(w3t, hf2.s, a2, 0, 0, 0);

        long e = waveBase + t * 16 + r;
        if (g == 0 && e < E)
            ((float4*)out)[e] = make_float4(d3[0], d3[1], d3[2], d3[3]);
    };

    if (XMODE == 1) {
        u32x4 Asl, Ash, Atl, Ath, Bsl, Bsh, Btl, Bth;
        #define GATHER(P, t) { \
            const u32x4* ps = (const u32x4*)(xb + (long)sidx[t] * LAT); \
            const u32x4* pt = (const u32x4*)(xb + (long)tidx[t] * LAT); \
            P##sl = ps[g]; P##sh = ps[4 + g]; P##tl = pt[g]; P##th = pt[4 + g]; }
        #define COMPUTE(P, t) { \
            union { short8 s; u32x4 u; } af0, af1, af2, af3; \
            _Pragma("unroll") \
            for (int q = 0; q < 4; ++q) { \
                unsigned mn, mx; \
                mnmx_word(P##sl[q], P##tl[q], mn, mx); af0.u[q] = mn; af2.u[q] = mx; \
                mnmx_word(P##sh[q], P##th[q], mn, mx); af1.u[q] = mn; af3.u[q] = mx; \
            } \
            compute_tile(af0.s, af1.s, af2.s, af3.s, t); }

        GATHER(A, 0)
        GATHER(B, 1)
        COMPUTE(A, 0)
        GATHER(A, 2)
        COMPUTE(B, 1)
        GATHER(B, 3)
        COMPUTE(A, 2)
        COMPUTE(B, 3)
        #undef GATHER
        #undef COMPUTE
    } else {
        #pragma unroll
        for (int t = 0; t < 4; ++t) {
            const float4* ps = (const float4*)(xf + (long)sidx[t] * LAT);
            const float4* pt = (const float4*)(xf + (long)tidx[t] * LAT);
            float4 sa = ps[2 * g], sb = ps[2 * g + 1], sc = ps[8 + 2 * g], sd = ps[9 + 2 * g];
            float4 ta = pt[2 * g], tb = pt[2 * g + 1], tc = pt[8 + 2 * g], td = pt[9 + 2 * g];
            MnMx4 m0 = mnmx4(sa, ta);
            MnMx4 m1 = mnmx4(sb, tb);
            MnMx4 m2 = mnmx4(sc, tc);
            MnMx4 m3 = mnmx4(sd, td);
            union { short8 s; u32x4 u; } af0, af1, af2, af3;
            af0.u[0] = m0.w0; af0.u[1] = m0.w1; af2.u[0] = m0.x0; af2.u[1] = m0.x1;
            af0.u[2] = m1.w0; af0.u[3] = m1.w1; af2.u[2] = m1.x0; af2.u[3] = m1.x1;
            af1.u[0] = m2.w0; af1.u[1] = m2.w1; af3.u[0] = m2.x0; af3.u[1] = m2.x1;
            af1.u[2] = m3.w0; af1.u[3] = m3.w1; af3.u[2] = m3.x0; af3.u[3] = m3.x1;
            compute_tile(af0.s, af1.s, af2.s, af3.s, t);
        }
    }
}

// ---------- fallback (tiny ws): per-thread fp32 kernel ----------
__global__ __launch_bounds__(256) void edge_pred_fp32_kernel(
    const float* __restrict__ x, const int* __restrict__ ei,
    const float* __restrict__ Wd, const float* __restrict__ bd,
    const float* __restrict__ W1, const float* __restrict__ b1,
    const float* __restrict__ W2, const float* __restrict__ b2,
    const float* __restrict__ W3, const float* __restrict__ b3,
    float* __restrict__ out, int E)
{
    int e = blockIdx.x * blockDim.x + threadIdx.x;
    if (e >= E) return;
    int s = ei[e];
    int t = ei[E + e];
    const float4* xs4 = (const float4*)(x + (long)s * 64);
    const float4* xt4 = (const float4*)(x + (long)t * 64);
    float h[HID];
    #pragma unroll
    for (int j = 0; j < HID; ++j) h[j] = b1[j];
    float d0 = bd[0], d1 = bd[1], d2 = bd[2], d3 = bd[3];
    #pragma unroll 2
    for (int c = 0; c < 16; ++c) {
        float4 a = xs4[c];
        float4 b = xt4[c];
        float mn[4] = {fminf(a.x,b.x), fminf(a.y,b.y), fminf(a.z,b.z), fminf(a.w,b.w)};
        float mx[4] = {fmaxf(a.x,b.x), fmaxf(a.y,b.y), fmaxf(a.z,b.z), fmaxf(a.w,b.w)};
        #pragma unroll
        for (int q = 0; q < 4; ++q) {
            int lidx = c * 4 + q;
            const float* wlo = W1 + lidx * HID;
            const float* whi = W1 + (64 + lidx) * HID;
            #pragma unroll
            for (int j = 0; j < HID; ++j) { h[j] += mn[q]*wlo[j]; h[j] += mx[q]*whi[j]; }
            const float* dlo = Wd + lidx * 4;
            const float* dhi = Wd + (64 + lidx) * 4;
            d0 += mn[q]*dlo[0] + mx[q]*dhi[0];
            d1 += mn[q]*dlo[1] + mx[q]*dhi[1];
            d2 += mn[q]*dlo[2] + mx[q]*dhi[2];
            d3 += mn[q]*dlo[3] + mx[q]*dhi[3];
        }
    }
    float h1[HID];
    #pragma unroll
    for (int j = 0; j < HID; ++j) h1[j] = fmaxf(h[j], 0.0f);
    float s2[HID];
    #pragma unroll
    for (int j = 0; j < HID; ++j) s2[j] = b2[j] + h1[j];
    #pragma unroll 4
    for (int k = 0; k < HID; ++k) {
        const float* w2r = W2 + k * HID;
        #pragma unroll
        for (int j = 0; j < HID; ++j) s2[j] += h1[k] * w2r[j];
    }
    float o0 = b3[0] + d0, o1 = b3[1] + d1, o2 = b3[2] + d2, o3 = b3[3] + d3;
    #pragma unroll
    for (int k = 0; k < HID; ++k) {
        float hk = fmaxf(s2[k], 0.0f);
        const float* w3r = W3 + k * 4;
        o0 += hk*w3r[0]; o1 += hk*w3r[1]; o2 += hk*w3r[2]; o3 += hk*w3r[3];
    }
    *(float4*)(out + (long)e * 4) = make_float4(o0, o1, o2, o3);
}

extern "C" void kernel_launch(void* const* d_in, const int* in_sizes, int n_in,
                              void* d_out, int out_size, void* d_ws, size_t ws_size,
                              hipStream_t stream) {
    const float* x  = (const float*)d_in[0];
    const int*   ei = (const int*)d_in[1];
    const float* Wd = (const float*)d_in[2];
    const float* bd = (const float*)d_in[3];
    const float* W1 = (const float*)d_in[4];
    const float* b1 = (const float*)d_in[5];
    const float* W2 = (const float*)d_in[6];
    const float* b2 = (const float*)d_in[7];
    const float* W3 = (const float*)d_in[8];
    const float* b3 = (const float*)d_in[9];
    float* out = (float*)d_out;

    int E  = in_sizes[1] / 2;
    int NN = in_sizes[0] / LAT;

    size_t fbytes  = (size_t)NFRAG  * 64 * 16;   // 12 KB W1aug frags
    size_t f2bytes = (size_t)NFRAG2 * 64 * 16;   // 2 KB  W2aug frags
    size_t f3bytes = (size_t)NFRAG3 * 64 * 16;   // 1 KB  W3aug frag
    size_t fall    = fbytes + f2bytes + f3bytes;
    size_t fpad    = (fall + 255) & ~(size_t)255;
    size_t xbytes  = (size_t)NN * LAT * 2;       // bf16 x

    int grid = (E + EPB - 1) / EPB;
    if (ws_size >= fpad + xbytes) {
        unsigned short* frg  = (unsigned short*)d_ws;
        unsigned short* frg2 = (unsigned short*)((char*)d_ws + fbytes);
        unsigned short* frg3 = (unsigned short*)((char*)d_ws + fbytes + f2bytes);
        unsigned short* xb   = (unsigned short*)((char*)d_ws + fpad);
        int n8 = NN * LAT / 8;
        int prep_grid = 4 + (n8 + 255) / 256;
        hipLaunchKernelGGL(prep_kernel, dim3(prep_grid), dim3(256), 0, stream,
                           x, W1, Wd, W2, W3, frg, frg2, frg3, xb, n8);
        hipLaunchKernelGGL((edge_mfma_kernel<1>), dim3(grid), dim3(256), 0, stream,
                           x, xb, frg, frg2, frg3, ei, b1, bd, b2, b3, out, E);
    } else if (ws_size >= fall) {
        unsigned short* frg  = (unsigned short*)d_ws;
        unsigned short* frg2 = (unsigned short*)((char*)d_ws + fbytes);
        unsigned short* frg3 = (unsigned short*)((char*)d_ws + fbytes + f2bytes);
        hipLaunchKernelGGL(prep_kernel, dim3(4), dim3(256), 0, stream,
                           x, W1, Wd, W2, W3, frg, frg2, frg3,
                           (unsigned short*)nullptr, 0);
        hipLaunchKernelGGL((edge_mfma_kernel<0>), dim3(grid), dim3(256), 0, stream,
                           x, (const unsigned short*)nullptr, frg, frg2, frg3,
                           ei, b1, bd, b2, b3, out, E);
    } else {
        hipLaunchKernelGGL(edge_pred_fp32_kernel, dim3((E + 255) / 256), dim3(256), 0, stream,
                           x, ei, Wd, bd, W1, b1, W2, b2, W3, b3, out, E);
    }
}